// Round 7
// baseline (26164.526 us; speedup 1.0000x reference)
//
#include <hip/hip_runtime.h>
#include <hip/hip_bf16.h>

// KHopfield on MI355X — round 15.
// r12/r13/r14 all ran 26.1ms +-0.3% despite different code => shared cost is
// raw global traffic of the Bc=512 GEMM config (~130-190 MB/call at ~650GB/s
// effective; per-XCD L2 4MiB can't hold the 16-32MiB shared panels under
// round-robin dispatch). Fix: XCD-chunked grid swizzle (bijective, 256 blocks):
//   wgemm: one split-K z-slice per XCD -> S + memT slices (2MB+2MB) L2-resident
//   dist:  contiguous n-range per XCD  -> mem panels (2MB) L2-resident
// Kernel bodies and numerics verbatim from r14 (passed, absmax 0.0156).
// LEGACY mode: verbatim round-8 f32 path as fallback.

constexpr int   Bq    = 2048;
constexpr int   Nm    = 8192;
constexpr int   Dd    = 512;
constexpr int   KK    = 5;
constexpr float BETA  = 1.0f;
constexpr int   STEPS = 2;
constexpr int   KS    = 8;                 // split-K planes (both paths)
constexpr size_t PL   = (size_t)Bq * Dd;

#define DEV static __device__ __forceinline__

typedef __attribute__((ext_vector_type(8))) short           short8v; // 8 bf16
typedef __attribute__((ext_vector_type(8))) unsigned short  u16x8;
typedef __attribute__((ext_vector_type(4))) float           f32x4;

DEV float b2f(ushort u) { unsigned v = ((unsigned)u) << 16; float f; __builtin_memcpy(&f, &v, 4); return f; }
DEV ushort f2b(float f) { __hip_bfloat16 h = __float2bfloat16(f); ushort u; __builtin_memcpy(&u, &h, 2); return u; }
DEV float ldin(const void* p, int isf, size_t idx) {
    return isf ? ((const float*)p)[idx] : b2f(((const ushort*)p)[idx]);
}

__global__ __launch_bounds__(256) void detect_k(const ushort* __restrict__ xin,
                                                int* __restrict__ flag) {
    __shared__ int sb;
    if (threadIdx.x == 0) sb = 0;
    __syncthreads();
    int bad = 0;
    for (int i = threadIdx.x; i < 1024; i += 256) {
        float v = b2f(xin[i]);
        if (!(fabsf(v) < 64.0f)) bad = 1;
    }
    if (bad) atomicOr(&sb, 1);
    __syncthreads();
    if (threadIdx.x == 0) flag[0] = sb;     // 1 => inputs are f32
}

__global__ __launch_bounds__(256) void norms_k(const void* __restrict__ xin,
                                               const void* __restrict__ memin,
                                               const int* __restrict__ flag,
                                               float* __restrict__ x2,
                                               float* __restrict__ m2) {
    int row = blockIdx.x;
    int isf = flag[0];
    const void* src; size_t base; float* dst;
    if (row < Nm) { src = memin; base = (size_t)row * Dd; dst = m2 + row; }
    else          { src = xin; base = (size_t)(row - Nm) * Dd; dst = x2 + (row - Nm); }
    int tid = threadIdx.x, lane = tid & 63, wave = tid >> 6;
    float s = 0.f;
    for (int i = tid; i < Dd; i += 256) { float v = ldin(src, isf, base + i); s += v * v; }
    for (int off = 32; off; off >>= 1) s += __shfl_down(s, off, 64);
    __shared__ float ws[4];
    if (lane == 0) ws[wave] = s;
    __syncthreads();
    if (tid == 0) dst[0] = ws[0] + ws[1] + ws[2] + ws[3];
}

// ======================= FULL-mode kernels =======================

__global__ __launch_bounds__(256) void convHL_k(const void* __restrict__ src,
                                                const int* __restrict__ flag,
                                                ushort* __restrict__ H,
                                                ushort* __restrict__ L,
                                                int nQuads, int qoff) {
    int isf = flag[0];
    for (int i = blockIdx.x * 256 + threadIdx.x; i < nQuads; i += gridDim.x * 256) {
        float v0, v1, v2, v3;
        if (isf) {
            float4 t = ((const float4*)src)[qoff + i];
            v0 = t.x; v1 = t.y; v2 = t.z; v3 = t.w;
        } else {
            ushort4 t = ((const ushort4*)src)[qoff + i];
            v0 = b2f(t.x); v1 = b2f(t.y); v2 = b2f(t.z); v3 = b2f(t.w);
        }
        ushort4 h, l;
        h.x = f2b(v0); l.x = f2b(v0 - b2f(h.x));
        h.y = f2b(v1); l.y = f2b(v1 - b2f(h.y));
        h.z = f2b(v2); l.z = f2b(v2 - b2f(h.z));
        h.w = f2b(v3); l.w = f2b(v3 - b2f(h.w));
        ((ushort4*)H)[i] = h;
        ((ushort4*)L)[i] = l;
    }
}

__global__ __launch_bounds__(256) void convT_k(const void* __restrict__ memin,
                                               const int* __restrict__ flag,
                                               ushort* __restrict__ TH,
                                               ushort* __restrict__ TL) {
    __shared__ float tile[64][65];
    const int isf = flag[0];
    const int n0 = blockIdx.x * 64, d0 = blockIdx.y * 64;
    const int tid = threadIdx.x;
    {
        const int r = tid >> 2, cseg = tid & 3;
#pragma unroll
        for (int j = 0; j < 16; ++j)
            tile[r][cseg * 16 + j] = ldin(memin, isf, (size_t)(n0 + r) * Dd + d0 + cseg * 16 + j);
    }
    __syncthreads();
    {
        const int drow = tid >> 2, nseg = tid & 3;
        size_t base = (size_t)(d0 + drow) * Nm + n0 + nseg * 16;
#pragma unroll
        for (int c = 0; c < 2; ++c) {
            u16x8 h, l;
#pragma unroll
            for (int j = 0; j < 8; ++j) {
                float v = tile[nseg * 16 + c * 8 + j][drow];
                ushort hu = f2b(v);
                h[j] = hu;
                l[j] = f2b(v - b2f(hu));
            }
            *(u16x8*)&TH[base + c * 8] = h;
            *(u16x8*)&TL[base + c * 8] = l;
        }
    }
}

__global__ __launch_bounds__(256) void copyR_k(const ushort* __restrict__ srcH,
                                               const ushort* __restrict__ srcL,
                                               ushort* __restrict__ dstH,
                                               ushort* __restrict__ dstL, int n8) {
    int i = blockIdx.x * 256 + threadIdx.x;
    if (i < n8) {
        ((u16x8*)dstH)[i] = ((const u16x8*)srcH)[i];
        ((u16x8*)dstL)[i] = ((const u16x8*)srcL)[i];
    }
}

// ---- dist GEMM, XCD-swizzled 1D grid (64*nbm blocks, nbm=Bc/128)
// XCD x owns a contiguous n-range across all m-blocks (mem panels L2-resident)
__global__ __launch_bounds__(256) void distSW_k(const ushort* __restrict__ Ah,
                                                const ushort* __restrict__ Al,
                                                const ushort* __restrict__ Mh,
                                                const ushort* __restrict__ Ml,
                                                float* __restrict__ S,
                                                const float* __restrict__ a2,
                                                const float* __restrict__ m2,
                                                int ab0, float negBeta, int nbm) {
    __shared__ ushort TA[2][4][128][8];   // [plane][kc][row][8]  16 KiB
    __shared__ ushort TB[2][4][128][8];
    const int tid = threadIdx.x, lane = tid & 63, wid = tid >> 6;
    const int wm = wid >> 1, wn = wid & 1;
    const int chunk = gridDim.x >> 3;
    const int ids = (blockIdx.x & 7) * chunk + (blockIdx.x >> 3);
    const int nb = ids / nbm, mb = ids % nbm;
    const int m0 = mb * 128, n0 = nb * 128;
    const int srow = tid & 127, kb = tid >> 7;       // kb in {0,1}; chunks kb, kb+2
    const size_t baseA = (size_t)(ab0 + m0 + srow) * Dd;
    const size_t baseB = (size_t)(n0 + srow) * Dd;

    f32x4 acc[4][4];
    const f32x4 z = {0.f, 0.f, 0.f, 0.f};
#pragma unroll
    for (int i = 0; i < 4; ++i)
#pragma unroll
        for (int j = 0; j < 4; ++j) acc[i][j] = z;

    for (int k0 = 0; k0 < Dd; k0 += 32) {
        u16x8 rah0 = *(const u16x8*)&Ah[baseA + k0 + kb * 8];
        u16x8 rah1 = *(const u16x8*)&Ah[baseA + k0 + (kb + 2) * 8];
        u16x8 ral0 = *(const u16x8*)&Al[baseA + k0 + kb * 8];
        u16x8 ral1 = *(const u16x8*)&Al[baseA + k0 + (kb + 2) * 8];
        u16x8 rbh0 = *(const u16x8*)&Mh[baseB + k0 + kb * 8];
        u16x8 rbh1 = *(const u16x8*)&Mh[baseB + k0 + (kb + 2) * 8];
        u16x8 rbl0 = *(const u16x8*)&Ml[baseB + k0 + kb * 8];
        u16x8 rbl1 = *(const u16x8*)&Ml[baseB + k0 + (kb + 2) * 8];
        __syncthreads();
        *(u16x8*)&TA[0][kb][srow][0]     = rah0;
        *(u16x8*)&TA[0][kb + 2][srow][0] = rah1;
        *(u16x8*)&TA[1][kb][srow][0]     = ral0;
        *(u16x8*)&TA[1][kb + 2][srow][0] = ral1;
        *(u16x8*)&TB[0][kb][srow][0]     = rbh0;
        *(u16x8*)&TB[0][kb + 2][srow][0] = rbh1;
        *(u16x8*)&TB[1][kb][srow][0]     = rbl0;
        *(u16x8*)&TB[1][kb + 2][srow][0] = rbl1;
        __syncthreads();

        const int rl = lane & 15, kc = lane >> 4;
        short8v ah[4], al[4];
#pragma unroll
        for (int fm = 0; fm < 4; ++fm) {
            const int ra_ = wm * 64 + fm * 16 + rl;
            ah[fm] = *(const short8v*)&TA[0][kc][ra_][0];
            al[fm] = *(const short8v*)&TA[1][kc][ra_][0];
        }
#pragma unroll
        for (int fn = 0; fn < 4; ++fn) {
            const int rb_ = wn * 64 + fn * 16 + rl;
            short8v bh = *(const short8v*)&TB[0][kc][rb_][0];
            short8v bl = *(const short8v*)&TB[1][kc][rb_][0];
#pragma unroll
            for (int fm = 0; fm < 4; ++fm) {
                acc[fm][fn] = __builtin_amdgcn_mfma_f32_16x16x32_bf16(ah[fm], bh, acc[fm][fn], 0, 0, 0);
                acc[fm][fn] = __builtin_amdgcn_mfma_f32_16x16x32_bf16(al[fm], bh, acc[fm][fn], 0, 0, 0);
                acc[fm][fn] = __builtin_amdgcn_mfma_f32_16x16x32_bf16(ah[fm], bl, acc[fm][fn], 0, 0, 0);
            }
        }
    }

    const int col = lane & 15, r0 = (lane >> 4) * 4;   // C/D: col=lane&15, row=(lane>>4)*4+q
#pragma unroll
    for (int fm = 0; fm < 4; ++fm)
#pragma unroll
        for (int fn = 0; fn < 4; ++fn) {
            const int n = n0 + wn * 64 + fn * 16 + col;
            const float mm2 = m2[n];
#pragma unroll
            for (int q = 0; q < 4; ++q) {
                const int m = m0 + wm * 64 + fm * 16 + r0 + q;
                const float d = a2[m] + mm2 - 2.0f * acc[fm][fn][q];
                S[(size_t)m * Nm + n] = negBeta * fmaxf(d, 0.0f);
            }
        }
}

template <int TRF>
DEV float wtr(float s, float p0, float p1) {
    if (TRF == 1) return expf(s - p0) * p1;                // softmax weight
    else          return 1.0f / (1.0f + expf(-(s + p0)));  // LML sigmoid
}

// ---- fused weight GEMM, XCD-swizzled 1D grid (8*nbm*ks blocks)
// XCD x owns split-K z-slice(s): S cols + memT cols slice L2-resident.
template <int TRF>
__global__ __launch_bounds__(256) void wgemmSW_k(const float* __restrict__ Sx,
                                                 const float* __restrict__ rowpar,
                                                 const ushort* __restrict__ MTh,
                                                 const ushort* __restrict__ MTl,
                                                 float* __restrict__ part,
                                                 int planeSz, int nzLen, int nbm) {
    __shared__ ushort TW[2][4][128][8];   // [plane][kc][brow][8]  16 KiB
    __shared__ ushort TB[2][4][64][8];    // [plane][kc][drow][8]   8 KiB
    const int tid = threadIdx.x, lane = tid & 63, wid = tid >> 6;
    const int wm = wid >> 1, wn = wid & 1;
    const int chunk = gridDim.x >> 3;
    const int ids = (blockIdx.x & 7) * chunk + (blockIdx.x >> 3);
    const int zb  = ids / (8 * nbm);
    const int rem = ids % (8 * nbm);
    const int bb  = rem / 8, db = rem % 8;
    const int d0 = db * 64, b0 = bb * 128;
    const int nz0 = zb * nzLen;

    const int wrow = tid & 127, wkb = tid >> 7;      // W: chunks wkb, wkb+2
    const int brow = tid & 63,  bkc = tid >> 6;      // B: one chunk
    const size_t baseS = (size_t)(b0 + wrow) * Nm;
    const size_t baseB = (size_t)(d0 + brow) * Nm;
    const float p0 = rowpar[(b0 + wrow) * 2 + 0];
    const float p1 = rowpar[(b0 + wrow) * 2 + 1];

    f32x4 acc[4][2];
    const f32x4 z = {0.f, 0.f, 0.f, 0.f};
#pragma unroll
    for (int i = 0; i < 4; ++i)
#pragma unroll
        for (int j = 0; j < 2; ++j) acc[i][j] = z;

#define PACKW(SV, H, L, I) { float w_ = wtr<TRF>(SV, p0, p1); ushort hu_ = f2b(w_); \
                             H[I] = hu_; L[I] = f2b(w_ - b2f(hu_)); }

    for (int nc = nz0; nc < nz0 + nzLen; nc += 32) {
        float4 sA = *(const float4*)&Sx[baseS + nc + wkb * 8];
        float4 sB = *(const float4*)&Sx[baseS + nc + wkb * 8 + 4];
        float4 sC = *(const float4*)&Sx[baseS + nc + (wkb + 2) * 8];
        float4 sD = *(const float4*)&Sx[baseS + nc + (wkb + 2) * 8 + 4];
        u16x8 rbh = *(const u16x8*)&MTh[baseB + nc + bkc * 8];
        u16x8 rbl = *(const u16x8*)&MTl[baseB + nc + bkc * 8];
        u16x8 wh0, wl0, wh1, wl1;
        PACKW(sA.x, wh0, wl0, 0) PACKW(sA.y, wh0, wl0, 1)
        PACKW(sA.z, wh0, wl0, 2) PACKW(sA.w, wh0, wl0, 3)
        PACKW(sB.x, wh0, wl0, 4) PACKW(sB.y, wh0, wl0, 5)
        PACKW(sB.z, wh0, wl0, 6) PACKW(sB.w, wh0, wl0, 7)
        PACKW(sC.x, wh1, wl1, 0) PACKW(sC.y, wh1, wl1, 1)
        PACKW(sC.z, wh1, wl1, 2) PACKW(sC.w, wh1, wl1, 3)
        PACKW(sD.x, wh1, wl1, 4) PACKW(sD.y, wh1, wl1, 5)
        PACKW(sD.z, wh1, wl1, 6) PACKW(sD.w, wh1, wl1, 7)
        __syncthreads();
        *(u16x8*)&TW[0][wkb][wrow][0]     = wh0;
        *(u16x8*)&TW[0][wkb + 2][wrow][0] = wh1;
        *(u16x8*)&TW[1][wkb][wrow][0]     = wl0;
        *(u16x8*)&TW[1][wkb + 2][wrow][0] = wl1;
        *(u16x8*)&TB[0][bkc][brow][0]     = rbh;
        *(u16x8*)&TB[1][bkc][brow][0]     = rbl;
        __syncthreads();

        const int rl = lane & 15, kc = lane >> 4;
        short8v wfh[4], wfl[4];
#pragma unroll
        for (int fm = 0; fm < 4; ++fm) {
            const int rw_ = wm * 64 + fm * 16 + rl;
            wfh[fm] = *(const short8v*)&TW[0][kc][rw_][0];
            wfl[fm] = *(const short8v*)&TW[1][kc][rw_][0];
        }
#pragma unroll
        for (int fn = 0; fn < 2; ++fn) {
            const int rd_ = wn * 32 + fn * 16 + rl;
            short8v bh = *(const short8v*)&TB[0][kc][rd_][0];
            short8v bl = *(const short8v*)&TB[1][kc][rd_][0];
#pragma unroll
            for (int fm = 0; fm < 4; ++fm) {
                acc[fm][fn] = __builtin_amdgcn_mfma_f32_16x16x32_bf16(wfh[fm], bh, acc[fm][fn], 0, 0, 0);
                acc[fm][fn] = __builtin_amdgcn_mfma_f32_16x16x32_bf16(wfl[fm], bh, acc[fm][fn], 0, 0, 0);
                acc[fm][fn] = __builtin_amdgcn_mfma_f32_16x16x32_bf16(wfh[fm], bl, acc[fm][fn], 0, 0, 0);
            }
        }
    }
#undef PACKW

    float* pz = part + (size_t)zb * planeSz;
    const int col = lane & 15, r0 = (lane >> 4) * 4;
#pragma unroll
    for (int fm = 0; fm < 4; ++fm)
#pragma unroll
        for (int fn = 0; fn < 2; ++fn) {
            const int dc = d0 + wn * 32 + fn * 16 + col;
#pragma unroll
            for (int q = 0; q < 4; ++q) {
                const int br = b0 + wm * 64 + fm * 16 + r0 + q;
                pz[(size_t)br * Dd + dc] = acc[fm][fn][q];
            }
        }
}

__global__ __launch_bounds__(256) void reduceHL_k(const float* __restrict__ part,
                                                  ushort* __restrict__ Rh,
                                                  ushort* __restrict__ Rl,
                                                  float* __restrict__ r2w, int doNorm,
                                                  int planeSz, int ks) {
    int row = blockIdx.x, tid = threadIdx.x, lane = tid & 63, wave = tid >> 6;
    float sq = 0.f;
    for (int e = tid; e < Dd; e += 256) {
        float s = 0.f;
        for (int z = 0; z < ks; ++z) s += part[(size_t)z * planeSz + (size_t)row * Dd + e];
        ushort h = f2b(s);
        Rh[(size_t)row * Dd + e] = h;
        Rl[(size_t)row * Dd + e] = f2b(s - b2f(h));
        sq += s * s;
    }
    if (doNorm) {
        for (int off = 32; off; off >>= 1) sq += __shfl_down(sq, off, 64);
        __shared__ float ws[4];
        if (lane == 0) ws[wave] = sq;
        __syncthreads();
        if (tid == 0) r2w[row] = ws[0] + ws[1] + ws[2] + ws[3];
    }
}

__global__ __launch_bounds__(256) void combineHL_k(ushort* __restrict__ rhl,
                                                   float* __restrict__ r2all) {
    int row = blockIdx.x, tid = threadIdx.x, lane = tid & 63, wave = tid >> 6;
    float sq[5] = {0.f, 0.f, 0.f, 0.f, 0.f};
    for (int e = tid; e < Dd; e += 256) {
        size_t idx = (size_t)row * Dd + e;
        float v[5];
#pragma unroll
        for (int j = 0; j < 5; ++j)
            v[j] = b2f(rhl[(size_t)j * 2 * PL + idx]) + b2f(rhl[(size_t)j * 2 * PL + PL + idx]);
        float o[5];
        o[0] = v[0];
        o[1] = v[1] - v[0]; o[2] = v[2] - v[1]; o[3] = v[3] - v[2]; o[4] = v[4] - v[3];
#pragma unroll
        for (int j = 1; j < 5; ++j) {
            ushort h = f2b(o[j]);
            rhl[(size_t)j * 2 * PL + idx] = h;
            rhl[(size_t)j * 2 * PL + PL + idx] = f2b(o[j] - b2f(h));
        }
#pragma unroll
        for (int j = 0; j < 5; ++j) sq[j] += o[j] * o[j];
    }
    __shared__ float ws[5][4];
#pragma unroll
    for (int j = 0; j < 5; ++j) {
        float s = sq[j];
        for (int off = 32; off; off >>= 1) s += __shfl_down(s, off, 64);
        if (lane == 0) ws[j][wave] = s;
    }
    __syncthreads();
    if (tid < 5) r2all[tid * Bq + row] = ws[tid][0] + ws[tid][1] + ws[tid][2] + ws[tid][3];
}

__global__ __launch_bounds__(256) void boundF_k(const ushort* __restrict__ rhl,
                                                void* __restrict__ bounce,
                                                const int* __restrict__ flag) {
    size_t idx = (size_t)blockIdx.x * 256 + threadIdx.x;
    bool isf = flag[0] != 0;
#pragma unroll
    for (int j = 0; j < KK; ++j) {
        float v = b2f(rhl[(size_t)j * 2 * PL + idx]) + b2f(rhl[(size_t)j * 2 * PL + PL + idx]);
        if (isf) ((float*)bounce)[idx * KK + j] = v;
        else     ((ushort*)bounce)[idx * KK + j] = f2b(v);
    }
}

__global__ __launch_bounds__(256) void copyout_k(const uint4* __restrict__ src,
                                                 uint4* __restrict__ dst,
                                                 const int* __restrict__ flag) {
    size_t n16 = (flag[0] ? PL * KK * 4 : PL * KK * 2) / 16;
    for (size_t i = (size_t)blockIdx.x * 256 + threadIdx.x; i < n16;
         i += (size_t)gridDim.x * 256)
        dst[i] = src[i];
}

// ======================= shared stats kernels =======================

__global__ __launch_bounds__(256) void rowstats_k(const float* __restrict__ S,
                                                  float* __restrict__ stats) {
    int b = blockIdx.x, tid = threadIdx.x, lane = tid & 63, wave = tid >> 6;
    __shared__ float cbuf[1024];
    __shared__ int   ccnt;
    __shared__ float tops[256 * 6];
    __shared__ float stop[6];
    __shared__ float wred[16];
    __shared__ float bcast[5];
    const float* srow = S + (size_t)b * Nm;

    float tt[6];
#pragma unroll
    for (int q = 0; q < 6; ++q) tt[q] = -3.4e38f;
    for (int i = tid; i < Nm; i += 256) {
        float v = srow[i];
        if (v > tt[5]) {
            tt[5] = v;
#pragma unroll
            for (int q = 5; q > 0; --q)
                if (tt[q] > tt[q - 1]) { float tm = tt[q]; tt[q] = tt[q - 1]; tt[q - 1] = tm; }
        }
    }
#pragma unroll
    for (int q = 0; q < 6; ++q) tops[tid * 6 + q] = tt[q];
    if (tid == 0) ccnt = 0;
    __syncthreads();
    if (tid == 0) {
        float mt[6];
#pragma unroll
        for (int q = 0; q < 6; ++q) mt[q] = -3.4e38f;
        for (int i = 0; i < 256 * 6; ++i) {
            float v = tops[i];
            if (v > mt[5]) {
                mt[5] = v;
#pragma unroll
                for (int q = 5; q > 0; --q)
                    if (mt[q] > mt[q - 1]) { float tm = mt[q]; mt[q] = mt[q - 1]; mt[q - 1] = tm; }
            }
        }
#pragma unroll
        for (int q = 0; q < 6; ++q) stop[q] = mt[q];
    }
    __syncthreads();

    float smax = stop[0];
    float cutoff = stop[5] - 40.0f;
    float p = 0.f;
    for (int i = tid; i < Nm; i += 256) {
        float v = srow[i];
        p += expf(v - smax);
        if (v >= cutoff) {
            int idx = atomicAdd(&ccnt, 1);
            if (idx < 1024) cbuf[idx] = v;
        }
    }
    for (int off = 32; off; off >>= 1) p += __shfl_down(p, off, 64);
    if (lane == 0) wred[wave] = p;
    __syncthreads();
    if (tid == 0) bcast[4] = wred[0] + wred[1] + wred[2] + wred[3];
    __syncthreads();
    float denom = bcast[4];
    int cnt = min(ccnt, 1024);

    float lo[4], hi[4];
#pragma unroll
    for (int q = 0; q < 4; ++q) { lo[q] = -stop[q + 1] - 7.0f; hi[q] = -stop[q + 2] + 7.0f; }
    for (int it = 0; it < 48; ++it) {
        float mid[4], pp[4] = {0.f, 0.f, 0.f, 0.f};
#pragma unroll
        for (int q = 0; q < 4; ++q) mid[q] = 0.5f * (lo[q] + hi[q]);
        for (int i = tid; i < cnt; i += 256) {
            float v = cbuf[i];
#pragma unroll
            for (int q = 0; q < 4; ++q) pp[q] += 1.0f / (1.0f + expf(-(v + mid[q])));
        }
#pragma unroll
        for (int q = 0; q < 4; ++q) {
            float s = pp[q];
            for (int off = 32; off; off >>= 1) s += __shfl_down(s, off, 64);
            if (lane == 0) wred[wave * 4 + q] = s;
        }
        __syncthreads();
        if (tid == 0)
#pragma unroll
            for (int q = 0; q < 4; ++q) bcast[q] = wred[q] + wred[4 + q] + wred[8 + q] + wred[12 + q];
        __syncthreads();
#pragma unroll
        for (int q = 0; q < 4; ++q) {
            float f = bcast[q] - (float)(q + 2);
            if (f < 0.f) lo[q] = mid[q]; else hi[q] = mid[q];
        }
        __syncthreads();
    }
    if (tid == 0) {
        stats[b * 6 + 0] = smax;
        stats[b * 6 + 1] = denom;
#pragma unroll
        for (int q = 0; q < 4; ++q) stats[b * 6 + 2 + q] = 0.5f * (lo[q] + hi[q]);
    }
}

__global__ __launch_bounds__(256) void rowpar_stage1_k(const float* __restrict__ stats,
                                                       float* __restrict__ rowpar, int jj) {
    int b = blockIdx.x * 256 + threadIdx.x;
    if (b >= Bq) return;
    if (jj == 0) {
        rowpar[b * 2 + 0] = stats[b * 6 + 0];
        rowpar[b * 2 + 1] = 1.0f / stats[b * 6 + 1];
    } else {
        rowpar[b * 2 + 0] = stats[b * 6 + 1 + jj];
        rowpar[b * 2 + 1] = 0.0f;
    }
}

__global__ __launch_bounds__(256) void rowmax_denom_k(const float* __restrict__ S,
                                                      float* __restrict__ rowpar) {
    int b = blockIdx.x, tid = threadIdx.x, lane = tid & 63, wave = tid >> 6;
    __shared__ float wred[4];
    __shared__ float bc[1];
    const float* srow = S + (size_t)b * Nm;
    float mx = -3.4e38f;
    for (int i = tid; i < Nm; i += 256) mx = fmaxf(mx, srow[i]);
    for (int off = 32; off; off >>= 1) mx = fmaxf(mx, __shfl_down(mx, off, 64));
    if (lane == 0) wred[wave] = mx;
    __syncthreads();
    if (tid == 0) bc[0] = fmaxf(fmaxf(wred[0], wred[1]), fmaxf(wred[2], wred[3]));
    __syncthreads();
    mx = bc[0];
    float p = 0.f;
    for (int i = tid; i < Nm; i += 256) p += expf(srow[i] - mx);
    for (int off = 32; off; off >>= 1) p += __shfl_down(p, off, 64);
    __syncthreads();
    if (lane == 0) wred[wave] = p;
    __syncthreads();
    if (tid == 0) {
        rowpar[b * 2 + 0] = mx;
        rowpar[b * 2 + 1] = 1.0f / (wred[0] + wred[1] + wred[2] + wred[3]);
    }
}

// ======================= LEGACY (round-8) kernels =======================

__global__ __launch_bounds__(256) void distF2_k(const void* __restrict__ A,
                                                const int* __restrict__ flag, int aForceF,
                                                const void* __restrict__ memin,
                                                float* __restrict__ S,
                                                const float* __restrict__ a2,
                                                const float* __restrict__ m2,
                                                int ab0, float negBeta) {
    __shared__ float As[16][68];
    __shared__ float Bs[16][68];
    const int tid = threadIdx.x, tx = tid & 15, ty = tid >> 4;
    const int m0 = blockIdx.y * 64, n0 = blockIdx.x * 64;
    const int isfA = aForceF ? 1 : flag[0];
    const int isfB = flag[0];

    float acc[4][4];
#pragma unroll
    for (int i = 0; i < 4; ++i)
#pragma unroll
        for (int j = 0; j < 4; ++j) acc[i][j] = 0.f;

    for (int d0 = 0; d0 < Dd; d0 += 16) {
#pragma unroll
        for (int c = tid; c < 1024; c += 256) {
            int r = c >> 4, k = c & 15;
            As[k][r] = ldin(A, isfA, (size_t)(ab0 + m0 + r) * Dd + d0 + k);
            Bs[k][r] = ldin(memin, isfB, (size_t)(n0 + r) * Dd + d0 + k);
        }
        __syncthreads();
#pragma unroll
        for (int k = 0; k < 16; ++k) {
            float4 av = *(const float4*)&As[k][ty * 4];
            float4 bv = *(const float4*)&Bs[k][tx * 4];
            float a[4] = {av.x, av.y, av.z, av.w};
            float b[4] = {bv.x, bv.y, bv.z, bv.w};
#pragma unroll
            for (int i = 0; i < 4; ++i)
#pragma unroll
                for (int j = 0; j < 4; ++j) acc[i][j] = fmaf(a[i], b[j], acc[i][j]);
        }
        __syncthreads();
    }
#pragma unroll
    for (int i = 0; i < 4; ++i) {
        int m = m0 + ty * 4 + i;
        float4 o;
        float* po = (float*)&o;
#pragma unroll
        for (int j = 0; j < 4; ++j) {
            float d = a2[m] + m2[n0 + tx * 4 + j] - 2.0f * acc[i][j];
            po[j] = negBeta * fmaxf(d, 0.0f);
        }
        *(float4*)&S[(size_t)m * Nm + n0 + tx * 4] = o;
    }
}

template <int TRF>
__global__ __launch_bounds__(256) void wgemmG_k(const float* __restrict__ Sx,
                                                const void* __restrict__ memin,
                                                const int* __restrict__ flag,
                                                const float* __restrict__ rowpar,
                                                float* __restrict__ part, int planeSz) {
    __shared__ float Ws[16][68];
    __shared__ float Bs[16][68];
    const int tid = threadIdx.x, tx = tid & 15, ty = tid >> 4;
    const int d0 = blockIdx.x * 64, b0 = blockIdx.y * 64;
    const int kz = blockIdx.z * (Nm / KS);
    const int isf = flag[0];

    float acc[4][4];
#pragma unroll
    for (int i = 0; i < 4; ++i)
#pragma unroll
        for (int j = 0; j < 4; ++j) acc[i][j] = 0.f;

    for (int nc = kz; nc < kz + Nm / KS; nc += 16) {
#pragma unroll
        for (int c = tid; c < 1024; c += 256) {
            int r = c >> 4, k = c & 15;
            float s = Sx[(size_t)(b0 + r) * Nm + nc + k];
            float p0 = rowpar[(b0 + r) * 2 + 0];
            float w;
            if constexpr (TRF == 1) w = expf(s - p0) * rowpar[(b0 + r) * 2 + 1];
            else                    w = 1.0f / (1.0f + expf(-(s + p0)));
            Ws[k][r] = w;
            int kk = c >> 6, dd = c & 63;
            Bs[kk][dd] = ldin(memin, isf, (size_t)(nc + kk) * Dd + d0 + dd);
        }
        __syncthreads();
#pragma unroll
        for (int k = 0; k < 16; ++k) {
            float4 av = *(const float4*)&Ws[k][ty * 4];
            float4 bv = *(const float4*)&Bs[k][tx * 4];
            float a[4] = {av.x, av.y, av.z, av.w};
            float b[4] = {bv.x, bv.y, bv.z, bv.w};
#pragma unroll
            for (int i = 0; i < 4; ++i)
#pragma unroll
                for (int j = 0; j < 4; ++j) acc[i][j] = fmaf(a[i], b[j], acc[i][j]);
        }
        __syncthreads();
    }
    float* pz = part + (size_t)blockIdx.z * planeSz;
#pragma unroll
    for (int i = 0; i < 4; ++i) {
        float4 o = {acc[i][0], acc[i][1], acc[i][2], acc[i][3]};
        *(float4*)&pz[(size_t)(b0 + ty * 4 + i) * Dd + d0 + tx * 4] = o;
    }
}

__global__ __launch_bounds__(256) void reduceN_k(const float* __restrict__ part,
                                                 float* __restrict__ Rj,
                                                 float* __restrict__ r2w, int doNorm,
                                                 int planeSz) {
    int row = blockIdx.x, tid = threadIdx.x, lane = tid & 63, wave = tid >> 6;
    float sq = 0.f;
    for (int e = tid; e < Dd; e += 256) {
        float s = 0.f;
#pragma unroll
        for (int z = 0; z < KS; ++z) s += part[(size_t)z * planeSz + (size_t)row * Dd + e];
        Rj[(size_t)row * Dd + e] = s;
        sq += s * s;
    }
    if (doNorm) {
        for (int off = 32; off; off >>= 1) sq += __shfl_down(sq, off, 64);
        __shared__ float ws[4];
        if (lane == 0) ws[wave] = sq;
        __syncthreads();
        if (tid == 0) r2w[row] = ws[0] + ws[1] + ws[2] + ws[3];
    }
}

__global__ __launch_bounds__(256) void combine_k(float* __restrict__ R,
                                                 float* __restrict__ r2all) {
    int row = blockIdx.x, tid = threadIdx.x, lane = tid & 63, wave = tid >> 6;
    float sq[5] = {0.f, 0.f, 0.f, 0.f, 0.f};
    for (int e = tid; e < Dd; e += 256) {
        size_t idx = (size_t)row * Dd + e;
        float r0 = R[idx], r1 = R[PL + idx], r2v = R[2 * PL + idx],
              r3 = R[3 * PL + idx], r4 = R[4 * PL + idx];
        float o1 = r1 - r0, o2 = r2v - r1, o3 = r3 - r2v, o4 = r4 - r3;
        R[PL + idx] = o1; R[2 * PL + idx] = o2; R[3 * PL + idx] = o3; R[4 * PL + idx] = o4;
        sq[0] += r0 * r0; sq[1] += o1 * o1; sq[2] += o2 * o2; sq[3] += o3 * o3; sq[4] += o4 * o4;
    }
    __shared__ float ws[5][4];
#pragma unroll
    for (int j = 0; j < 5; ++j) {
        float s = sq[j];
        for (int off = 32; off; off >>= 1) s += __shfl_down(s, off, 64);
        if (lane == 0) ws[j][wave] = s;
    }
    __syncthreads();
    if (tid < 5) r2all[tid * Bq + row] = ws[tid][0] + ws[tid][1] + ws[tid][2] + ws[tid][3];
}

__global__ __launch_bounds__(256) void final_k(const float* __restrict__ R,
                                               void* __restrict__ out,
                                               const int* __restrict__ flag) {
    size_t idx = (size_t)blockIdx.x * 256 + threadIdx.x;
    bool isf = flag[0] != 0;
#pragma unroll
    for (int j = 0; j < KK; ++j) {
        float v = R[(size_t)j * PL + idx];
        if (isf) ((float*)out)[idx * KK + j] = v;
        else     ((ushort*)out)[idx * KK + j] = f2b(v);
    }
}

// ======================= launcher =======================

extern "C" void kernel_launch(void* const* d_in, const int* in_sizes, int n_in,
                              void* d_out, int out_size, void* d_ws, size_t ws_size,
                              hipStream_t stream) {
    const void* xin   = d_in[0];
    const void* memin = d_in[1];

    const size_t MiB = 1048576ull, KiB = 1024ull;
    char* ws = (char*)d_ws;

    // ---- FULL config: Bc=512, ks=8, all operands in ws, rhl in d_out.
    const int    Bc   = 512;
    const int    ks   = KS;
    const size_t rhlB = 2ull * KK * PL * 2;                 // 20,971,520
    const size_t needWS = 56 * MiB + 192 * KiB;             // 58,916,864

    if ((size_t)out_size >= rhlB && ws_size >= needWS) {
        ushort* mh    = (ushort*)(ws + 0);                  // 8 MiB
        ushort* ml    = (ushort*)(ws + 8 * MiB);            // 8 MiB
        ushort* mth   = (ushort*)(ws + 16 * MiB);           // 8 MiB
        ushort* mtl   = (ushort*)(ws + 24 * MiB);           // 8 MiB
        float*  S     = (float*)(ws + 32 * MiB);            // 16 MiB
        float*  part  = (float*)(ws + 48 * MiB);            // 8 MiB
        char*   misc  = ws + 56 * MiB;                      // 192 KiB
        float*  m2    = (float*)(misc + 0);                 // 32 KiB
        float*  x2    = (float*)(misc + 32 * KiB);          //  8 KiB
        float*  stats = (float*)(misc + 40 * KiB);          // 48 KiB
        float*  rpar  = (float*)(misc + 88 * KiB);          // 16 KiB
        int*    flag  = (int*)  (misc + 104 * KiB);         //  4 B
        float*  r2all = (float*)(misc + 112 * KiB);         // 40 KiB
        ushort* rhl   = (ushort*)d_out;                     // 20.97 MB (d_out)
        ushort* asH   = (ushort*)part;                      // transient A slice
        ushort* asL   = asH + (size_t)Bc * Dd;              // (1 MiB total)
        void*   bounce = (void*)S;

        const int nbm     = Bc / 128;       // 4
        const int nChunk  = Bq / Bc;        // 4
        const int planeSz = Bc * Dd;        // 262144
        const int nzLen   = Nm / ks;        // 1024
        const int slice8  = Bc * Dd / 8;
        const int distGrid  = (Nm / 128) * nbm;   // 256 (1D, swizzled)
        const int wgemmGrid = 8 * nbm * ks;       // 256 (1D, swizzled)

        detect_k<<<1, 256, 0, stream>>>((const ushort*)xin, flag);
        norms_k<<<Nm + Bq, 256, 0, stream>>>(xin, memin, flag, x2, m2);
        convHL_k<<<2048, 256, 0, stream>>>(memin, flag, mh, ml, Nm * Dd / 4, 0);
        convT_k<<<dim3(Nm / 64, Dd / 64), 256, 0, stream>>>(memin, flag, mth, mtl);

        // ---- stage 1 ----
        for (int c = 0; c < nChunk; ++c) {
            int b0 = c * Bc;
            convHL_k<<<Bc / 2, 256, 0, stream>>>(xin, flag, asH, asL,
                                                 Bc * Dd / 4, b0 * Dd / 4);
            distSW_k<<<distGrid, 256, 0, stream>>>(
                asH, asL, mh, ml, S, x2 + b0, m2, 0, -BETA, nbm);
            rowstats_k<<<Bc, 256, 0, stream>>>(S, stats + (size_t)b0 * 6);
            for (int jj = 0; jj < KK; ++jj) {
                rowpar_stage1_k<<<Bq / 256, 256, 0, stream>>>(stats, rpar, jj);
                if (jj == 0)
                    wgemmSW_k<1><<<wgemmGrid, 256, 0, stream>>>(
                        S, rpar + (size_t)b0 * 2, mth, mtl, part, planeSz, nzLen, nbm);
                else
                    wgemmSW_k<2><<<wgemmGrid, 256, 0, stream>>>(
                        S, rpar + (size_t)b0 * 2, mth, mtl, part, planeSz, nzLen, nbm);
                ushort* Rh = rhl + (size_t)jj * 2 * PL + (size_t)b0 * Dd;
                ushort* Rl = rhl + (size_t)jj * 2 * PL + PL + (size_t)b0 * Dd;
                reduceHL_k<<<Bc, 256, 0, stream>>>(part, Rh, Rl, nullptr, 0, planeSz, ks);
            }
        }
        combineHL_k<<<Bq, 256, 0, stream>>>(rhl, r2all);

        // ---- hopfield refinement ----
        for (int st = 0; st < STEPS; ++st) {
            for (int jj = 0; jj < KK; ++jj) {
                ushort* Rhj = rhl + (size_t)jj * 2 * PL;
                ushort* Rlj = rhl + (size_t)jj * 2 * PL + PL;
                float* r2j = r2all + (size_t)jj * Bq;
                for (int c = 0; c < nChunk; ++c) {
                    int b0 = c * Bc;
                    copyR_k<<<(slice8 + 255) / 256, 256, 0, stream>>>(
                        Rhj + (size_t)b0 * Dd, Rlj + (size_t)b0 * Dd,
                        asH, asL, slice8);
                    distSW_k<<<distGrid, 256, 0, stream>>>(
                        asH, asL, mh, ml, S, r2j + b0, m2, 0, -BETA, nbm);
                    rowmax_denom_k<<<Bc, 256, 0, stream>>>(S, rpar + (size_t)b0 * 2);
                    wgemmSW_k<1><<<wgemmGrid, 256, 0, stream>>>(
                        S, rpar + (size_t)b0 * 2, mth, mtl, part, planeSz, nzLen, nbm);
                    reduceHL_k<<<Bc, 256, 0, stream>>>(
                        part, Rhj + (size_t)b0 * Dd, Rlj + (size_t)b0 * Dd,
                        r2j + b0, 1, planeSz, ks);
                }
            }
        }
        boundF_k<<<(int)(PL / 256), 256, 0, stream>>>(rhl, bounce, flag);
        copyout_k<<<2048, 256, 0, stream>>>((const uint4*)bounce, (uint4*)d_out, flag);
        return;
    }

    // ---- LEGACY mode (round-8 verbatim) ----
    float* part = (float*)d_out;                           // split-K partials in d_out tail
    float* R     = (float*)(ws + 0);                       // 20 MiB [5][Bq][Dd]
    float* m2    = (float*)(ws + 20 * MiB);                // 32 KiB
    float* x2    = (float*)(ws + 20 * MiB + 32 * KiB);     //  8 KiB
    float* stats = (float*)(ws + 20 * MiB + 48 * KiB);     // 48 KiB
    float* rpar  = (float*)(ws + 20 * MiB + 96 * KiB);     // 16 KiB
    int*   flag  = (int*)  (ws + 20 * MiB + 112 * KiB);    //  4 B
    float* r2all = (float*)(ws + 20 * MiB + 128 * KiB);    // 40 KiB [5][Bq]
    float* S     = (float*)(ws + 20 * MiB + 256 * KiB);    // Bc * 32 KiB

    int Bcl = 128;
    const int cand[4] = {1024, 512, 256, 128};
    for (int i = 0; i < 4; ++i) {
        size_t needWSl = 20 * MiB + 256 * KiB + (size_t)cand[i] * Nm * 4;
        size_t needOut = (size_t)KS * cand[i] * Dd * 4;
        if (needWSl <= ws_size && needOut <= (size_t)out_size) { Bcl = cand[i]; break; }
    }
    const int nChunk = Bq / Bcl;
    const int planeSz = Bcl * Dd;

    detect_k<<<1, 256, 0, stream>>>((const ushort*)xin, flag);
    norms_k<<<Nm + Bq, 256, 0, stream>>>(xin, memin, flag, x2, m2);

    for (int c = 0; c < nChunk; ++c) {
        int b0 = c * Bcl;
        distF2_k<<<dim3(Nm / 64, Bcl / 64), 256, 0, stream>>>(
            xin, flag, 0, memin, S, x2 + b0, m2, b0, -BETA);
        rowstats_k<<<Bcl, 256, 0, stream>>>(S, stats + (size_t)b0 * 6);
        for (int jj = 0; jj < KK; ++jj) {
            float* Rj = R + (size_t)jj * PL + (size_t)b0 * Dd;
            rowpar_stage1_k<<<Bq / 256, 256, 0, stream>>>(stats, rpar, jj);
            if (jj == 0)
                wgemmG_k<1><<<dim3(Dd / 64, Bcl / 64, KS), 256, 0, stream>>>(
                    S, memin, flag, rpar + (size_t)b0 * 2, part, planeSz);
            else
                wgemmG_k<2><<<dim3(Dd / 64, Bcl / 64, KS), 256, 0, stream>>>(
                    S, memin, flag, rpar + (size_t)b0 * 2, part, planeSz);
            reduceN_k<<<Bcl, 256, 0, stream>>>(part, Rj, nullptr, 0, planeSz);
        }
    }
    combine_k<<<Bq, 256, 0, stream>>>(R, r2all);

    for (int st = 0; st < STEPS; ++st) {
        for (int jj = 0; jj < KK; ++jj) {
            float* Rj = R + (size_t)jj * PL;
            float* r2j = r2all + (size_t)jj * Bq;
            for (int c = 0; c < nChunk; ++c) {
                int b0 = c * Bcl;
                distF2_k<<<dim3(Nm / 64, Bcl / 64), 256, 0, stream>>>(
                    Rj, flag, 1, memin, S, r2j + b0, m2, b0, -BETA);
                rowmax_denom_k<<<Bcl, 256, 0, stream>>>(S, rpar + (size_t)b0 * 2);
                wgemmG_k<1><<<dim3(Dd / 64, Bcl / 64, KS), 256, 0, stream>>>(
                    S, memin, flag, rpar + (size_t)b0 * 2, part, planeSz);
                reduceN_k<<<Bcl, 256, 0, stream>>>(
                    part, Rj + (size_t)b0 * Dd, r2j + b0, 1, planeSz);
            }
        }
    }
    final_k<<<(int)(PL / 256), 256, 0, stream>>>(R, d_out, flag);
}

// Round 9
// 10782.822 us; speedup vs baseline: 2.4265x; 2.4265x over previous
//
#include <hip/hip_runtime.h>
#include <hip/hip_bf16.h>

// KHopfield on MI355X — round 17 (= round 16 resubmitted; infra failure ate
// the previous run). Clean A/B vs the proven 10.1ms round-8 config:
// IDENTICAL skeleton, gating, buffers, grids, aux kernels. ONLY the two GEMM
// inner bodies change: f32 FMA -> hi/lo bf16 3-pass MFMA (r11-proven fragment
// layout), on-the-fly conversion in staging (named vectors only), W transform
// fused (r13 style), mem-transpose gathered per-j (coalesced across lanes).
// Rationale: r12-r15 proved cost is set by launch geometry+traffic at a
// ~700GB/s effective ceiling (r0 counters: wgemm 622GB/s, VALUBusy 57%).
// Keep the only proven geometry; cut the 57% VALU share with MFMA.

constexpr int   Bq    = 2048;
constexpr int   Nm    = 8192;
constexpr int   Dd    = 512;
constexpr int   KK    = 5;
constexpr float BETA  = 1.0f;
constexpr int   STEPS = 2;
constexpr int   KS    = 8;                 // wgemm split-K planes
constexpr size_t PL   = (size_t)Bq * Dd;

#define DEV static __device__ __forceinline__

typedef __attribute__((ext_vector_type(8))) short           short8v; // 8 bf16
typedef __attribute__((ext_vector_type(8))) unsigned short  u16x8;
typedef __attribute__((ext_vector_type(4))) float           f32x4;

DEV float b2f(ushort u) { unsigned v = ((unsigned)u) << 16; float f; __builtin_memcpy(&f, &v, 4); return f; }
DEV ushort f2b(float f) { __hip_bfloat16 h = __float2bfloat16(f); ushort u; __builtin_memcpy(&u, &h, 2); return u; }
DEV float ldin(const void* p, int isf, size_t idx) {
    return isf ? ((const float*)p)[idx] : b2f(((const ushort*)p)[idx]);
}

__global__ __launch_bounds__(256) void detect_k(const ushort* __restrict__ xin,
                                                int* __restrict__ flag) {
    __shared__ int sb;
    if (threadIdx.x == 0) sb = 0;
    __syncthreads();
    int bad = 0;
    for (int i = threadIdx.x; i < 1024; i += 256) {
        float v = b2f(xin[i]);
        if (!(fabsf(v) < 64.0f)) bad = 1;
    }
    if (bad) atomicOr(&sb, 1);
    __syncthreads();
    if (threadIdx.x == 0) flag[0] = sb;     // 1 => inputs are f32
}

__global__ __launch_bounds__(256) void norms_k(const void* __restrict__ xin,
                                               const void* __restrict__ memin,
                                               const int* __restrict__ flag,
                                               float* __restrict__ x2,
                                               float* __restrict__ m2) {
    int row = blockIdx.x;
    int isf = flag[0];
    const void* src; size_t base; float* dst;
    if (row < Nm) { src = memin; base = (size_t)row * Dd; dst = m2 + row; }
    else          { src = xin; base = (size_t)(row - Nm) * Dd; dst = x2 + (row - Nm); }
    int tid = threadIdx.x, lane = tid & 63, wave = tid >> 6;
    float s = 0.f;
    for (int i = tid; i < Dd; i += 256) { float v = ldin(src, isf, base + i); s += v * v; }
    for (int off = 32; off; off >>= 1) s += __shfl_down(s, off, 64);
    __shared__ float ws[4];
    if (lane == 0) ws[wave] = s;
    __syncthreads();
    if (tid == 0) dst[0] = ws[0] + ws[1] + ws[2] + ws[3];
}

// split helper: scalar value -> hi/lo bf16 into vector element I (const idx)
#define SPL(V, H, L, I) { ushort hu_ = f2b(V); H[I] = hu_; L[I] = f2b((V) - b2f(hu_)); }

// ---------- dist GEMM: 64x64 tile (r8 grid), MFMA hi/lo 3-pass inner body
__global__ __launch_bounds__(256) void distM_k(const void* __restrict__ A,
                                               const int* __restrict__ flag, int aForceF,
                                               const void* __restrict__ memin,
                                               float* __restrict__ S,
                                               const float* __restrict__ a2,
                                               const float* __restrict__ m2,
                                               int ab0, float negBeta) {
    __shared__ ushort TA[2][4][64][8];   // [plane][kc][row][8]  8 KiB
    __shared__ ushort TB[2][4][64][8];   // 8 KiB
    const int tid = threadIdx.x, lane = tid & 63, wid = tid >> 6;
    const int wm = wid >> 1, wn = wid & 1;
    const int m0 = blockIdx.y * 64, n0 = blockIdx.x * 64;
    const int isfA = aForceF ? 1 : flag[0];
    const int isfB = flag[0];
    const int r = tid & 63, kc = tid >> 6;

    f32x4 acc[2][2];
    const f32x4 z = {0.f, 0.f, 0.f, 0.f};
#pragma unroll
    for (int i = 0; i < 2; ++i)
#pragma unroll
        for (int j = 0; j < 2; ++j) acc[i][j] = z;

    for (int k0 = 0; k0 < Dd; k0 += 32) {
        const size_t offA = (size_t)(ab0 + m0 + r) * Dd + k0 + kc * 8;
        const size_t offB = (size_t)(n0 + r) * Dd + k0 + kc * 8;
        u16x8 ah, al, bh, bl;
        if (isfA) {
            float4 t0 = *(const float4*)((const float*)A + offA);
            float4 t1 = *(const float4*)((const float*)A + offA + 4);
            SPL(t0.x, ah, al, 0) SPL(t0.y, ah, al, 1) SPL(t0.z, ah, al, 2) SPL(t0.w, ah, al, 3)
            SPL(t1.x, ah, al, 4) SPL(t1.y, ah, al, 5) SPL(t1.z, ah, al, 6) SPL(t1.w, ah, al, 7)
        } else {
            u16x8 t = *(const u16x8*)((const ushort*)A + offA);
#pragma unroll
            for (int j = 0; j < 8; ++j) { ah[j] = t[j]; al[j] = 0; }
        }
        if (isfB) {
            float4 t0 = *(const float4*)((const float*)memin + offB);
            float4 t1 = *(const float4*)((const float*)memin + offB + 4);
            SPL(t0.x, bh, bl, 0) SPL(t0.y, bh, bl, 1) SPL(t0.z, bh, bl, 2) SPL(t0.w, bh, bl, 3)
            SPL(t1.x, bh, bl, 4) SPL(t1.y, bh, bl, 5) SPL(t1.z, bh, bl, 6) SPL(t1.w, bh, bl, 7)
        } else {
            u16x8 t = *(const u16x8*)((const ushort*)memin + offB);
#pragma unroll
            for (int j = 0; j < 8; ++j) { bh[j] = t[j]; bl[j] = 0; }
        }
        __syncthreads();   // protect previous iteration's fragment reads
        *(u16x8*)&TA[0][kc][r][0] = ah;
        *(u16x8*)&TA[1][kc][r][0] = al;
        *(u16x8*)&TB[0][kc][r][0] = bh;
        *(u16x8*)&TB[1][kc][r][0] = bl;
        __syncthreads();

        const int rl = lane & 15, kq = lane >> 4;
        short8v a0h = *(const short8v*)&TA[0][kq][wm * 32 + rl][0];
        short8v a1h = *(const short8v*)&TA[0][kq][wm * 32 + 16 + rl][0];
        short8v a0l = *(const short8v*)&TA[1][kq][wm * 32 + rl][0];
        short8v a1l = *(const short8v*)&TA[1][kq][wm * 32 + 16 + rl][0];
        short8v b0h = *(const short8v*)&TB[0][kq][wn * 32 + rl][0];
        short8v b1h = *(const short8v*)&TB[0][kq][wn * 32 + 16 + rl][0];
        short8v b0l = *(const short8v*)&TB[1][kq][wn * 32 + rl][0];
        short8v b1l = *(const short8v*)&TB[1][kq][wn * 32 + 16 + rl][0];

        acc[0][0] = __builtin_amdgcn_mfma_f32_16x16x32_bf16(a0h, b0h, acc[0][0], 0, 0, 0);
        acc[0][0] = __builtin_amdgcn_mfma_f32_16x16x32_bf16(a0l, b0h, acc[0][0], 0, 0, 0);
        acc[0][0] = __builtin_amdgcn_mfma_f32_16x16x32_bf16(a0h, b0l, acc[0][0], 0, 0, 0);
        acc[0][1] = __builtin_amdgcn_mfma_f32_16x16x32_bf16(a0h, b1h, acc[0][1], 0, 0, 0);
        acc[0][1] = __builtin_amdgcn_mfma_f32_16x16x32_bf16(a0l, b1h, acc[0][1], 0, 0, 0);
        acc[0][1] = __builtin_amdgcn_mfma_f32_16x16x32_bf16(a0h, b1l, acc[0][1], 0, 0, 0);
        acc[1][0] = __builtin_amdgcn_mfma_f32_16x16x32_bf16(a1h, b0h, acc[1][0], 0, 0, 0);
        acc[1][0] = __builtin_amdgcn_mfma_f32_16x16x32_bf16(a1l, b0h, acc[1][0], 0, 0, 0);
        acc[1][0] = __builtin_amdgcn_mfma_f32_16x16x32_bf16(a1h, b0l, acc[1][0], 0, 0, 0);
        acc[1][1] = __builtin_amdgcn_mfma_f32_16x16x32_bf16(a1h, b1h, acc[1][1], 0, 0, 0);
        acc[1][1] = __builtin_amdgcn_mfma_f32_16x16x32_bf16(a1l, b1h, acc[1][1], 0, 0, 0);
        acc[1][1] = __builtin_amdgcn_mfma_f32_16x16x32_bf16(a1h, b1l, acc[1][1], 0, 0, 0);
    }

    const int col = lane & 15, r0 = (lane >> 4) * 4;   // C/D: col=lane&15, row=(lane>>4)*4+q
#pragma unroll
    for (int fm = 0; fm < 2; ++fm)
#pragma unroll
        for (int fn = 0; fn < 2; ++fn) {
            const int n = n0 + wn * 32 + fn * 16 + col;
            const float mm2 = m2[n];
#pragma unroll
            for (int q = 0; q < 4; ++q) {
                const int m = m0 + wm * 32 + fm * 16 + r0 + q;
                const float d = a2[m] + mm2 - 2.0f * acc[fm][fn][q];
                S[(size_t)m * Nm + n] = negBeta * fmaxf(d, 0.0f);
            }
        }
}

// ---------- weight transform (scalar, no arrays)
template <int TRF>
DEV float wtr(float s, float p0, float p1) {
    if (TRF == 1) return expf(s - p0) * p1;                // softmax weight
    else          return 1.0f / (1.0f + expf(-(s + p0)));  // LML sigmoid
}

#define PACKW(SV, H, L, I) { float w_ = wtr<TRF>(SV, p0, p1); ushort hu_ = f2b(w_); \
                             H[I] = hu_; L[I] = f2b(w_ - b2f(hu_)); }

// ---------- weight GEMM: 64x64 tile (r8 grid), fused W transform, MFMA 3-pass
template <int TRF>
__global__ __launch_bounds__(256) void wgemmM_k(const float* __restrict__ Sx,
                                                const void* __restrict__ memin,
                                                const int* __restrict__ flag,
                                                const float* __restrict__ rowpar,
                                                float* __restrict__ part, int planeSz) {
    __shared__ ushort TW[2][4][64][8];   // [plane][kc][brow][8]  8 KiB
    __shared__ ushort TB[2][4][64][8];   // [plane][kc][drow][8]  8 KiB
    const int tid = threadIdx.x, lane = tid & 63, wid = tid >> 6;
    const int wm = wid >> 1, wn = wid & 1;
    const int d0 = blockIdx.x * 64, b0 = blockIdx.y * 64;
    const int kz = blockIdx.z * (Nm / KS);
    const int isf = flag[0];
    const int r = tid & 63, kc = tid >> 6;
    const float p0 = rowpar[(b0 + r) * 2 + 0];
    const float p1 = rowpar[(b0 + r) * 2 + 1];

    f32x4 acc[2][2];
    const f32x4 z = {0.f, 0.f, 0.f, 0.f};
#pragma unroll
    for (int i = 0; i < 2; ++i)
#pragma unroll
        for (int j = 0; j < 2; ++j) acc[i][j] = z;

    for (int nc = kz; nc < kz + Nm / KS; nc += 32) {
        // W row (b0+r), n-cols nc+kc*8 .. +8 (f32 S, coalesced 32B/lane)
        float4 s0 = *(const float4*)&Sx[(size_t)(b0 + r) * Nm + nc + kc * 8];
        float4 s1 = *(const float4*)&Sx[(size_t)(b0 + r) * Nm + nc + kc * 8 + 4];
        u16x8 wh, wl;
        PACKW(s0.x, wh, wl, 0) PACKW(s0.y, wh, wl, 1) PACKW(s0.z, wh, wl, 2) PACKW(s0.w, wh, wl, 3)
        PACKW(s1.x, wh, wl, 4) PACKW(s1.y, wh, wl, 5) PACKW(s1.z, wh, wl, 6) PACKW(s1.w, wh, wl, 7)
        // memT row (d0+r), n-cols nc+kc*8 .. +8 (per-j coalesced across lanes)
        u16x8 bh, bl;
#pragma unroll
        for (int j = 0; j < 8; ++j) {
            float v = ldin(memin, isf, (size_t)(nc + kc * 8 + j) * Dd + d0 + r);
            SPL(v, bh, bl, j)
        }
        __syncthreads();
        *(u16x8*)&TW[0][kc][r][0] = wh;
        *(u16x8*)&TW[1][kc][r][0] = wl;
        *(u16x8*)&TB[0][kc][r][0] = bh;
        *(u16x8*)&TB[1][kc][r][0] = bl;
        __syncthreads();

        const int rl = lane & 15, kq = lane >> 4;
        short8v w0h = *(const short8v*)&TW[0][kq][wm * 32 + rl][0];
        short8v w1h = *(const short8v*)&TW[0][kq][wm * 32 + 16 + rl][0];
        short8v w0l = *(const short8v*)&TW[1][kq][wm * 32 + rl][0];
        short8v w1l = *(const short8v*)&TW[1][kq][wm * 32 + 16 + rl][0];
        short8v b0h = *(const short8v*)&TB[0][kq][wn * 32 + rl][0];
        short8v b1h = *(const short8v*)&TB[0][kq][wn * 32 + 16 + rl][0];
        short8v b0l = *(const short8v*)&TB[1][kq][wn * 32 + rl][0];
        short8v b1l = *(const short8v*)&TB[1][kq][wn * 32 + 16 + rl][0];

        acc[0][0] = __builtin_amdgcn_mfma_f32_16x16x32_bf16(w0h, b0h, acc[0][0], 0, 0, 0);
        acc[0][0] = __builtin_amdgcn_mfma_f32_16x16x32_bf16(w0l, b0h, acc[0][0], 0, 0, 0);
        acc[0][0] = __builtin_amdgcn_mfma_f32_16x16x32_bf16(w0h, b0l, acc[0][0], 0, 0, 0);
        acc[0][1] = __builtin_amdgcn_mfma_f32_16x16x32_bf16(w0h, b1h, acc[0][1], 0, 0, 0);
        acc[0][1] = __builtin_amdgcn_mfma_f32_16x16x32_bf16(w0l, b1h, acc[0][1], 0, 0, 0);
        acc[0][1] = __builtin_amdgcn_mfma_f32_16x16x32_bf16(w0h, b1l, acc[0][1], 0, 0, 0);
        acc[1][0] = __builtin_amdgcn_mfma_f32_16x16x32_bf16(w1h, b0h, acc[1][0], 0, 0, 0);
        acc[1][0] = __builtin_amdgcn_mfma_f32_16x16x32_bf16(w1l, b0h, acc[1][0], 0, 0, 0);
        acc[1][0] = __builtin_amdgcn_mfma_f32_16x16x32_bf16(w1h, b0l, acc[1][0], 0, 0, 0);
        acc[1][1] = __builtin_amdgcn_mfma_f32_16x16x32_bf16(w1h, b1h, acc[1][1], 0, 0, 0);
        acc[1][1] = __builtin_amdgcn_mfma_f32_16x16x32_bf16(w1l, b1h, acc[1][1], 0, 0, 0);
        acc[1][1] = __builtin_amdgcn_mfma_f32_16x16x32_bf16(w1h, b1l, acc[1][1], 0, 0, 0);
    }

    float* pz = part + (size_t)blockIdx.z * planeSz;
    const int col = lane & 15, r0 = (lane >> 4) * 4;
#pragma unroll
    for (int fm = 0; fm < 2; ++fm)
#pragma unroll
        for (int fn = 0; fn < 2; ++fn) {
            const int dc = d0 + wn * 32 + fn * 16 + col;
#pragma unroll
            for (int q = 0; q < 4; ++q) {
                const int br = b0 + wm * 32 + fm * 16 + r0 + q;
                pz[(size_t)br * Dd + dc] = acc[fm][fn][q];
            }
        }
}

// ---------- reduce KS partials -> Rj rows (+ optional row sumsq) [r8 verbatim]
__global__ __launch_bounds__(256) void reduceN_k(const float* __restrict__ part,
                                                 float* __restrict__ Rj,
                                                 float* __restrict__ r2w, int doNorm,
                                                 int planeSz) {
    int row = blockIdx.x, tid = threadIdx.x, lane = tid & 63, wave = tid >> 6;
    float sq = 0.f;
    for (int e = tid; e < Dd; e += 256) {
        float s = 0.f;
#pragma unroll
        for (int z = 0; z < KS; ++z) s += part[(size_t)z * planeSz + (size_t)row * Dd + e];
        Rj[(size_t)row * Dd + e] = s;
        sq += s * s;
    }
    if (doNorm) {
        for (int off = 32; off; off >>= 1) sq += __shfl_down(sq, off, 64);
        __shared__ float ws[4];
        if (lane == 0) ws[wave] = sq;
        __syncthreads();
        if (tid == 0) r2w[row] = ws[0] + ws[1] + ws[2] + ws[3];
    }
}

// ---------- per-row stats [r8 verbatim]
__global__ __launch_bounds__(256) void rowstats_k(const float* __restrict__ S,
                                                  float* __restrict__ stats) {
    int b = blockIdx.x, tid = threadIdx.x, lane = tid & 63, wave = tid >> 6;
    __shared__ float cbuf[1024];
    __shared__ int   ccnt;
    __shared__ float tops[256 * 6];
    __shared__ float stop[6];
    __shared__ float wred[16];
    __shared__ float bcast[5];
    const float* srow = S + (size_t)b * Nm;

    float tt[6];
#pragma unroll
    for (int q = 0; q < 6; ++q) tt[q] = -3.4e38f;
    for (int i = tid; i < Nm; i += 256) {
        float v = srow[i];
        if (v > tt[5]) {
            tt[5] = v;
#pragma unroll
            for (int q = 5; q > 0; --q)
                if (tt[q] > tt[q - 1]) { float tm = tt[q]; tt[q] = tt[q - 1]; tt[q - 1] = tm; }
        }
    }
#pragma unroll
    for (int q = 0; q < 6; ++q) tops[tid * 6 + q] = tt[q];
    if (tid == 0) ccnt = 0;
    __syncthreads();
    if (tid == 0) {
        float mt[6];
#pragma unroll
        for (int q = 0; q < 6; ++q) mt[q] = -3.4e38f;
        for (int i = 0; i < 256 * 6; ++i) {
            float v = tops[i];
            if (v > mt[5]) {
                mt[5] = v;
#pragma unroll
                for (int q = 5; q > 0; --q)
                    if (mt[q] > mt[q - 1]) { float tm = mt[q]; mt[q] = mt[q - 1]; mt[q - 1] = tm; }
            }
        }
#pragma unroll
        for (int q = 0; q < 6; ++q) stop[q] = mt[q];
    }
    __syncthreads();

    float smax = stop[0];
    float cutoff = stop[5] - 40.0f;
    float p = 0.f;
    for (int i = tid; i < Nm; i += 256) {
        float v = srow[i];
        p += expf(v - smax);
        if (v >= cutoff) {
            int idx = atomicAdd(&ccnt, 1);
            if (idx < 1024) cbuf[idx] = v;
        }
    }
    for (int off = 32; off; off >>= 1) p += __shfl_down(p, off, 64);
    if (lane == 0) wred[wave] = p;
    __syncthreads();
    if (tid == 0) bcast[4] = wred[0] + wred[1] + wred[2] + wred[3];
    __syncthreads();
    float denom = bcast[4];
    int cnt = min(ccnt, 1024);

    float lo[4], hi[4];
#pragma unroll
    for (int q = 0; q < 4; ++q) { lo[q] = -stop[q + 1] - 7.0f; hi[q] = -stop[q + 2] + 7.0f; }
    for (int it = 0; it < 48; ++it) {
        float mid[4], pp[4] = {0.f, 0.f, 0.f, 0.f};
#pragma unroll
        for (int q = 0; q < 4; ++q) mid[q] = 0.5f * (lo[q] + hi[q]);
        for (int i = tid; i < cnt; i += 256) {
            float v = cbuf[i];
#pragma unroll
            for (int q = 0; q < 4; ++q) pp[q] += 1.0f / (1.0f + expf(-(v + mid[q])));
        }
#pragma unroll
        for (int q = 0; q < 4; ++q) {
            float s = pp[q];
            for (int off = 32; off; off >>= 1) s += __shfl_down(s, off, 64);
            if (lane == 0) wred[wave * 4 + q] = s;
        }
        __syncthreads();
        if (tid == 0)
#pragma unroll
            for (int q = 0; q < 4; ++q) bcast[q] = wred[q] + wred[4 + q] + wred[8 + q] + wred[12 + q];
        __syncthreads();
#pragma unroll
        for (int q = 0; q < 4; ++q) {
            float f = bcast[q] - (float)(q + 2);
            if (f < 0.f) lo[q] = mid[q]; else hi[q] = mid[q];
        }
        __syncthreads();
    }
    if (tid == 0) {
        stats[b * 6 + 0] = smax;
        stats[b * 6 + 1] = denom;
#pragma unroll
        for (int q = 0; q < 4; ++q) stats[b * 6 + 2 + q] = 0.5f * (lo[q] + hi[q]);
    }
}

__global__ __launch_bounds__(256) void rowpar_stage1_k(const float* __restrict__ stats,
                                                       float* __restrict__ rowpar, int jj) {
    int b = blockIdx.x * 256 + threadIdx.x;
    if (b >= Bq) return;
    if (jj == 0) {
        rowpar[b * 2 + 0] = stats[b * 6 + 0];
        rowpar[b * 2 + 1] = 1.0f / stats[b * 6 + 1];
    } else {
        rowpar[b * 2 + 0] = stats[b * 6 + 1 + jj];
        rowpar[b * 2 + 1] = 0.0f;
    }
}

__global__ __launch_bounds__(256) void rowmax_denom_k(const float* __restrict__ S,
                                                      float* __restrict__ rowpar) {
    int b = blockIdx.x, tid = threadIdx.x, lane = tid & 63, wave = tid >> 6;
    __shared__ float wred[4];
    __shared__ float bc[1];
    const float* srow = S + (size_t)b * Nm;
    float mx = -3.4e38f;
    for (int i = tid; i < Nm; i += 256) mx = fmaxf(mx, srow[i]);
    for (int off = 32; off; off >>= 1) mx = fmaxf(mx, __shfl_down(mx, off, 64));
    if (lane == 0) wred[wave] = mx;
    __syncthreads();
    if (tid == 0) bc[0] = fmaxf(fmaxf(wred[0], wred[1]), fmaxf(wred[2], wred[3]));
    __syncthreads();
    mx = bc[0];
    float p = 0.f;
    for (int i = tid; i < Nm; i += 256) p += expf(srow[i] - mx);
    for (int off = 32; off; off >>= 1) p += __shfl_down(p, off, 64);
    __syncthreads();
    if (lane == 0) wred[wave] = p;
    __syncthreads();
    if (tid == 0) {
        rowpar[b * 2 + 0] = mx;
        rowpar[b * 2 + 1] = 1.0f / (wred[0] + wred[1] + wred[2] + wred[3]);
    }
}

// ---------- successive differences + row norms [r8 verbatim]
__global__ __launch_bounds__(256) void combine_k(float* __restrict__ R,
                                                 float* __restrict__ r2all) {
    int row = blockIdx.x, tid = threadIdx.x, lane = tid & 63, wave = tid >> 6;
    float sq[5] = {0.f, 0.f, 0.f, 0.f, 0.f};
    for (int e = tid; e < Dd; e += 256) {
        size_t idx = (size_t)row * Dd + e;
        float r0 = R[idx], r1 = R[PL + idx], r2v = R[2 * PL + idx],
              r3 = R[3 * PL + idx], r4 = R[4 * PL + idx];
        float o1 = r1 - r0, o2 = r2v - r1, o3 = r3 - r2v, o4 = r4 - r3;
        R[PL + idx] = o1; R[2 * PL + idx] = o2; R[3 * PL + idx] = o3; R[4 * PL + idx] = o4;
        sq[0] += r0 * r0; sq[1] += o1 * o1; sq[2] += o2 * o2; sq[3] += o3 * o3; sq[4] += o4 * o4;
    }
    __shared__ float ws[5][4];
#pragma unroll
    for (int j = 0; j < 5; ++j) {
        float s = sq[j];
        for (int off = 32; off; off >>= 1) s += __shfl_down(s, off, 64);
        if (lane == 0) ws[j][wave] = s;
    }
    __syncthreads();
    if (tid < 5) r2all[tid * Bq + row] = ws[tid][0] + ws[tid][1] + ws[tid][2] + ws[tid][3];
}

__global__ __launch_bounds__(256) void final_k(const float* __restrict__ R,
                                               void* __restrict__ out,
                                               const int* __restrict__ flag) {
    size_t idx = (size_t)blockIdx.x * 256 + threadIdx.x;
    bool isf = flag[0] != 0;
#pragma unroll
    for (int j = 0; j < KK; ++j) {
        float v = R[(size_t)j * PL + idx];
        if (isf) ((float*)out)[idx * KK + j] = v;
        else     ((ushort*)out)[idx * KK + j] = f2b(v);
    }
}

// ======================= launcher [r8 verbatim except GEMM names] ==========

extern "C" void kernel_launch(void* const* d_in, const int* in_sizes, int n_in,
                              void* d_out, int out_size, void* d_ws, size_t ws_size,
                              hipStream_t stream) {
    const void* xin   = d_in[0];
    const void* memin = d_in[1];

    const size_t MiB = 1048576ull, KiB = 1024ull;
    char* ws = (char*)d_ws;
    float* R     = (float*)(ws + 0);                       // 20 MiB [5][Bq][Dd]
    float* m2    = (float*)(ws + 20 * MiB);                // 32 KiB
    float* x2    = (float*)(ws + 20 * MiB + 32 * KiB);     //  8 KiB
    float* stats = (float*)(ws + 20 * MiB + 48 * KiB);     // 48 KiB
    float* rpar  = (float*)(ws + 20 * MiB + 96 * KiB);     // 16 KiB
    int*   flag  = (int*)  (ws + 20 * MiB + 112 * KiB);    //  4 B
    float* r2all = (float*)(ws + 20 * MiB + 128 * KiB);    // 40 KiB [5][Bq]
    float* S     = (float*)(ws + 20 * MiB + 256 * KiB);    // Bc * 32 KiB

    // wgemm split-K partials live in d_out's dead tail (dead before final_k)
    float* part = (float*)d_out;                           // KS * Bc * 512 * 4

    int Bc = 128;
    const int cand[4] = {1024, 512, 256, 128};
    for (int i = 0; i < 4; ++i) {
        size_t needWS  = 20 * MiB + 256 * KiB + (size_t)cand[i] * Nm * 4;
        size_t needOut = (size_t)KS * cand[i] * Dd * 4;
        if (needWS <= ws_size && needOut <= (size_t)out_size) { Bc = cand[i]; break; }
    }
    const int nChunk = Bq / Bc;
    const int planeSz = Bc * Dd;

    detect_k<<<1, 256, 0, stream>>>((const ushort*)xin, flag);
    norms_k<<<Nm + Bq, 256, 0, stream>>>(xin, memin, flag, x2, m2);

    // ---- stage 1 ----
    for (int c = 0; c < nChunk; ++c) {
        int b0 = c * Bc;
        distM_k<<<dim3(Nm / 64, Bc / 64), 256, 0, stream>>>(
            xin, flag, 0, memin, S, x2 + b0, m2, b0, -BETA);
        rowstats_k<<<Bc, 256, 0, stream>>>(S, stats + (size_t)b0 * 6);
        for (int jj = 0; jj < KK; ++jj) {
            float* Rj = R + (size_t)jj * PL + (size_t)b0 * Dd;
            rowpar_stage1_k<<<Bq / 256, 256, 0, stream>>>(stats, rpar, jj);
            if (jj == 0)
                wgemmM_k<1><<<dim3(Dd / 64, Bc / 64, KS), 256, 0, stream>>>(
                    S, memin, flag, rpar + (size_t)b0 * 2, part, planeSz);
            else
                wgemmM_k<2><<<dim3(Dd / 64, Bc / 64, KS), 256, 0, stream>>>(
                    S, memin, flag, rpar + (size_t)b0 * 2, part, planeSz);
            reduceN_k<<<Bc, 256, 0, stream>>>(part, Rj, nullptr, 0, planeSz);
        }
    }
    combine_k<<<Bq, 256, 0, stream>>>(R, r2all);

    // ---- hopfield refinement ----
    for (int st = 0; st < STEPS; ++st) {
        for (int jj = 0; jj < KK; ++jj) {
            float* Rj = R + (size_t)jj * PL;
            float* r2j = r2all + (size_t)jj * Bq;
            for (int c = 0; c < nChunk; ++c) {
                int b0 = c * Bc;
                distM_k<<<dim3(Nm / 64, Bc / 64), 256, 0, stream>>>(
                    Rj, flag, 1, memin, S, r2j + b0, m2, b0, -BETA);
                rowmax_denom_k<<<Bc, 256, 0, stream>>>(S, rpar + (size_t)b0 * 2);
                wgemmM_k<1><<<dim3(Dd / 64, Bc / 64, KS), 256, 0, stream>>>(
                    S, memin, flag, rpar + (size_t)b0 * 2, part, planeSz);
                reduceN_k<<<Bc, 256, 0, stream>>>(
                    part, Rj + (size_t)b0 * Dd, r2j + b0, 1, planeSz);
            }
        }
    }
    final_k<<<(int)(PL / 256), 256, 0, stream>>>(R, d_out, flag);
}